// Round 12
// baseline (196.138 us; speedup 1.0000x reference)
//
#include <hip/hip_runtime.h>

#define D     512
#define HW    (D * D)
#define BLOCK 256

typedef float f4 __attribute__((ext_vector_type(4)));

// ---------------------------------------------------------------------------
// R12: persistent-block pipeline. 1024 blocks = 16 images x 64 blocks.
// Fast region (rows 8..511) is the LINEAR pixel range [4096, 262144): each
// thread owns 4 tiles (16 px) at byte offsets v0 + k*262144. Register double-
// buffer A/B: next tile's 4 global_load_dwordx4 (asm, saddr form) issue before
// current tile's compute; counted vmcnt waits (in-order semantics) keep 4
// loads always in flight and never wait on stores. Edge strip fused into
// blocks 0..31 of each image before the drain. Tests the last theory standing:
// per-wave launch/drain overhead (32K short waves -> 4K long waves).
// ---------------------------------------------------------------------------

#define GLOADS(dst, off, base) \
    asm volatile("global_load_dwordx4 %0, %1, %2" \
        : "=v"(dst) : "v"(off), "s"(base) : "memory")

#define WAITV(n) do { \
    asm volatile("s_waitcnt vmcnt(" #n ")" ::: "memory"); \
    __builtin_amdgcn_sched_barrier(0); } while (0)

// ---- corner samples per image (exact f32 replication of reference) --------
__global__ void __launch_bounds__(64) corner_kernel(
    const float* __restrict__ im1, const float* __restrict__ im2,
    float* __restrict__ wsS)
{
    int n = blockIdx.x;
    int t = threadIdx.x;
    if (t >= 6) return;
    const float WF = 1.0f - (510.999f - 510.0f);
    const float WC = 1.0f - (511.0f - 510.999f);
    const float* im = (t < 3) ? im1 : im2;
    int c = (t < 3) ? t : t - 3;
    const float* ch = im + (size_t)n * 3 * HW + (size_t)c * HW;
    float s = (WF * WF) * ch[510 + D * 510] + (WC * WF) * ch[510 + D * 511]
            + (WF * WC) * ch[511 + D * 510] + (WC * WC) * ch[511 + D * 511];
    wsS[n * 8 + t] = s;     // [0..2]=S1, [3..5]=S2
}

// Fast-path per-pixel math (identical expressions to passing kernels).
__device__ __forceinline__ void fast_px(float fi, float fj, float cx, float cy,
    float m1, float m2, const float S1[3], const float S2[3],
    float* oob, float r[3])
{
    float tot = m1 + m2;
    float inv = 1.0f / tot;
    float m1n = m1 * inv, m2n = m2 * inv;
    float rx1 = (fi + cx) * 512.0f, ry1 = (fj + cy) * 512.0f;
    float rx2 = (fi - cx) * 512.0f, ry2 = (fj - cy) * 512.0f;
    float dx1 = rx1 - 510.999f, dy1 = ry1 - 510.999f;
    float dx2 = rx2 - 510.999f, dy2 = ry2 - 510.999f;
    *oob += dx1 * dx1 + dy1 * dy1 + dx2 * dx2 + dy2 * dy2;
    r[0] = m1n * S1[0] + m2n * S2[0];
    r[1] = m1n * S1[1] + m2n * S2[1];
    r[2] = m1n * S1[2] + m2n * S2[2];
}

// General path: full reference bilinear with per-lane gathers (ind = y + D*x).
__device__ __forceinline__ void samp_gather(const float* __restrict__ im,
    float rx, float ry, float m, float r3[3], float* oob)
{
    float cxq = fminf(fmaxf(rx, 0.001f), 510.999f);
    float cyq = fminf(fmaxf(ry, 0.001f), 510.999f);
    float dx = rx - cxq, dy = ry - cyq;
    *oob += dx * dx + dy * dy;
    float xff = floorf(cxq), xcf = ceilf(cxq);
    float yff = floorf(cyq), ycf = ceilf(cyq);
    float wxf = 1.0f - (cxq - xff), wxc = 1.0f - (xcf - cxq);
    float wyf = 1.0f - (cyq - yff), wyc = 1.0f - (ycf - cyq);
    float w00 = wxf * wyf, w10 = wxc * wyf, w01 = wxf * wyc, w11 = wxc * wyc;
    int xf = (int)xff, xc = (int)xcf, yf = (int)yff, yc = (int)ycf;
    int i00 = yf + D * xf, i10 = yf + D * xc;
    int i01 = yc + D * xf, i11 = yc + D * xc;
#pragma unroll
    for (int c = 0; c < 3; ++c) {
        const float* __restrict__ ch = im + (size_t)c * HW;
        r3[c] += m * (w00 * ch[i00] + w10 * ch[i10] + w01 * ch[i01] + w11 * ch[i11]);
    }
}

// Full reference per-pixel (round-0 proven body): writes out, adds full oob.
__device__ __forceinline__ void ref_px(const float* __restrict__ base1,
    const float* __restrict__ base2, const float S1[3], const float S2[3],
    int i, int j, float cx, float cy, float m1v, float m2v,
    float* __restrict__ outp, size_t ob_pp, float* oob)
{
    float tot = m1v + m2v;
    float inv = 1.0f / tot;
    float m1n = m1v * inv, m2n = m2v * inv;
    float fi = (float)i, fj = (float)j;

    float rx1 = (fi + cx) * 512.0f, ry1 = (fj + cy) * 512.0f;
    float rx2 = (fi - cx) * 512.0f, ry2 = (fj - cy) * 512.0f;

    bool fast = ((fi - fabsf(cx)) * 512.0f >= 510.999f)
             && ((fj - fabsf(cy)) * 512.0f >= 510.999f);

    float r3[3];
    if (fast) {
        float dx1 = rx1 - 510.999f, dy1 = ry1 - 510.999f;
        float dx2 = rx2 - 510.999f, dy2 = ry2 - 510.999f;
        *oob += dx1 * dx1 + dy1 * dy1 + dx2 * dx2 + dy2 * dy2;
        r3[0] = m1n * S1[0] + m2n * S2[0];
        r3[1] = m1n * S1[1] + m2n * S2[1];
        r3[2] = m1n * S1[2] + m2n * S2[2];
    } else {
        r3[0] = r3[1] = r3[2] = 0.0f;
        samp_gather(base1, rx1, ry1, m1n, r3, oob);
        samp_gather(base2, rx2, ry2, m2n, r3, oob);
    }
    outp[ob_pp]          = r3[0];
    outp[ob_pp + HW]     = r3[1];
    outp[ob_pp + 2 * HW] = r3[2];
}

// One fast tile: 4 px from registers; NT stores; returns tile's oob sum.
__device__ __forceinline__ float tile_compute(
    f4 cx4, f4 cy4, f4 m14, f4 m24, float fi, float fj,
    const float S1[3], const float S2[3],
    float* __restrict__ baseO, unsigned voff, bool own)
{
    float to = 0.0f;
    float ra[3], rbv[3], rc[3], rd[3];
    fast_px(fi, fj + 0.0f, cx4.x, cy4.x, m14.x, m24.x, S1, S2, &to, ra);
    fast_px(fi, fj + 1.0f, cx4.y, cy4.y, m14.y, m24.y, S1, S2, &to, rbv);
    fast_px(fi, fj + 2.0f, cx4.z, cy4.z, m14.z, m24.z, S1, S2, &to, rc);
    fast_px(fi, fj + 3.0f, cx4.w, cy4.w, m14.w, m24.w, S1, S2, &to, rd);
    if (own) {
        float* p = (float*)((char*)baseO + voff);
        f4 v0 = {ra[0], rbv[0], rc[0], rd[0]};
        f4 v1 = {ra[1], rbv[1], rc[1], rd[1]};
        f4 v2 = {ra[2], rbv[2], rc[2], rd[2]};
        __builtin_nontemporal_store(v0, (f4*)p);
        __builtin_nontemporal_store(v1, (f4*)(p + HW));
        __builtin_nontemporal_store(v2, (f4*)(p + 2 * HW));
    }
    return to;
}

// 1024 persistent blocks: 64 per image. Blocks 0..31 of each image also own
// one edge unit (strip rows 0..7 U cols 0..7) before entering the fast loop.
__global__ void __launch_bounds__(BLOCK) main_kernel(
    const float* __restrict__ im1, const float* __restrict__ im2,
    const float* __restrict__ C,   const float* __restrict__ M1,
    const float* __restrict__ M2,  float* __restrict__ out,
    const float* __restrict__ wsS, float* __restrict__ partials)
{
    int b  = blockIdx.x;
    int t  = threadIdx.x;
    int n  = b >> 6;                 // 64 blocks per image
    int bl = b & 63;

    size_t cb = (size_t)n * 2 * HW, mb = (size_t)n * HW, ob = (size_t)n * 3 * HW;
    const float* baseCx = C + cb;
    const float* baseCy = C + cb + HW;
    const float* baseM1 = M1 + mb;
    const float* baseM2 = M2 + mb;
    float*       baseO  = out + ob;

    const float* sp = wsS + n * 8;
    float S1[3] = {sp[0], sp[1], sp[2]};
    float S2[3] = {sp[3], sp[4], sp[5]};
    // Pin S into registers BEFORE the vmcnt drain so no compiler waitcnt for
    // these loads lands inside the pipelined loop.
    asm volatile("" :: "v"(S1[0]), "v"(S1[1]), "v"(S1[2]),
                       "v"(S2[0]), "v"(S2[1]), "v"(S2[2]));

    // ---------------- edge unit (blocks 0..31 of each image) ---------------
    float oob_e = 0.0f;
    if (bl < 32) {
        const float* base1 = im1 + (size_t)n * 3 * HW;
        const float* base2 = im2 + (size_t)n * 3 * HW;
        int i, j; bool valid;
        if (bl < 16) {               // region A: rows 0..7, half-row each
            i = bl >> 1;
            j = ((bl & 1) << 8) + t;
            valid = true;
        } else {                     // region B: rows 8..511, cols 0..7
            int q = bl - 16;
            i = 8 + (q << 5) + (t >> 3);
            j = t & 7;
            valid = (i < D);
        }
        if (valid) {
            size_t pp = (size_t)i * D + j;
            ref_px(base1, base2, S1, S2, i, j,
                   C[cb + pp], C[cb + HW + pp], M1[mb + pp], M2[mb + pp],
                   out, ob + pp, &oob_e);
        }
    }

    // ---------------- persistent fast stream: 4 tiles per thread -----------
    // group g0 in [0,16384); tile k covers pixels 4096+4*(g0+k*16384) .. +3
    int g0 = (bl << 8) + t;
    bool own   = (g0 & 127) >= 2;    // col-groups 0,1 owned by edge units
    bool lastv = (bl < 60);          // tile 3 valid only for blocks 0..59
    int  row0  = 8 + (g0 >> 7);
    float fj   = (float)((g0 & 127) << 2);
    unsigned v0 = 16384u + 16u * (unsigned)g0;   // byte offset of tile 0
    unsigned v1 = v0 + 262144u;
    unsigned v2 = v1 + 262144u;
    unsigned v3 = lastv ? (v2 + 262144u) : v0;   // clamped dummy for tail

    float oob_f = 0.0f;
    f4 cxA, cyA, m1A, m2A, cxB, cyB, m1B, m2B;

    // drain edge/S traffic so asm vmcnt counts are exact from here on
    asm volatile("s_waitcnt vmcnt(0)" ::: "memory");
    __builtin_amdgcn_sched_barrier(0);

    GLOADS(cxA, v0, baseCx); GLOADS(cyA, v0, baseCy);
    GLOADS(m1A, v0, baseM1); GLOADS(m2A, v0, baseM2);
    GLOADS(cxB, v1, baseCx); GLOADS(cyB, v1, baseCy);
    GLOADS(m1B, v1, baseM1); GLOADS(m2B, v1, baseM2);

    // T0: outstanding = A(4)+B(4) -> oldest 4 (A) done
    WAITV(4);
    oob_f += tile_compute(cxA, cyA, m1A, m2A, (float)row0, fj, S1, S2, baseO, v0, own);

    // T1: prefetch T2 into A; outstanding <= B(4)+st0(3)+A2(4)=11 -> vmcnt(7)
    GLOADS(cxA, v2, baseCx); GLOADS(cyA, v2, baseCy);
    GLOADS(m1A, v2, baseM1); GLOADS(m2A, v2, baseM2);
    WAITV(7);
    oob_f += tile_compute(cxB, cyB, m1B, m2B, (float)(row0 + 128), fj, S1, S2, baseO, v1, own);

    // T2: prefetch T3 into B (dummy for tail blocks); vmcnt(7) covers A2
    GLOADS(cxB, v3, baseCx); GLOADS(cyB, v3, baseCy);
    GLOADS(m1B, v3, baseM1); GLOADS(m2B, v3, baseM2);
    WAITV(7);
    oob_f += tile_compute(cxA, cyA, m1A, m2A, (float)(row0 + 256), fj, S1, S2, baseO, v2, own);

    // T3: outstanding <= st1(3)+B3(4)+st2(3) -> vmcnt(3) covers B3
    WAITV(3);
    if (lastv)
        oob_f += tile_compute(cxB, cyB, m1B, m2B, (float)(row0 + 384), fj, S1, S2, baseO, v3, own);

    // ---- per-wave oob partial (no barrier, no LDS) ----
    float oob = oob_e + (own ? oob_f : 0.0f);
    for (int off = 32; off > 0; off >>= 1)
        oob += __shfl_down(oob, off, 64);
    int lane = t & 63, w = t >> 6;
    if (lane == 0)
        partials[(b << 2) + w] = oob;
}

__global__ void __launch_bounds__(BLOCK) reduce_kernel(
    const float* __restrict__ partials, int nparts,
    float* __restrict__ out_last, double scale)
{
    double s = 0.0;
    for (int i = threadIdx.x; i < nparts; i += BLOCK)
        s += (double)partials[i];
    for (int off = 32; off > 0; off >>= 1)
        s += __shfl_down(s, off, 64);

    __shared__ double sm[BLOCK / 64];
    int lane = threadIdx.x & 63;
    int w    = threadIdx.x >> 6;
    if (lane == 0) sm[w] = s;
    __syncthreads();
    if (threadIdx.x == 0)
        *out_last = (float)((sm[0] + sm[1] + sm[2] + sm[3]) * scale);
}

extern "C" void kernel_launch(void* const* d_in, const int* in_sizes, int n_in,
                              void* d_out, int out_size, void* d_ws, size_t ws_size,
                              hipStream_t stream) {
    const float* im1 = (const float*)d_in[0];
    const float* im2 = (const float*)d_in[1];
    const float* C   = (const float*)d_in[2];
    const float* M1  = (const float*)d_in[3];
    const float* M2  = (const float*)d_in[4];
    float* out = (float*)d_out;
    float* ws  = (float*)d_ws;

    int N = in_sizes[3] / HW;        // M1 is [N,1,H,W]
    int blocks = N * 64;             // persistent: 4 tiles per thread

    float* wsS   = ws;               // N*8 corner values
    float* parts = ws + (size_t)N * 8;

    corner_kernel<<<N, 64, 0, stream>>>(im1, im2, wsS);
    main_kernel<<<blocks, BLOCK, 0, stream>>>(im1, im2, C, M1, M2, out, wsS, parts);

    int nparts = blocks * 4;
    // loss = sum / (N*2*HW) / D^2 * 1e-4  (a and b share the mean count)
    double scale = 1.0 / ((double)N * 2.0 * (double)HW) / (double)HW * 1e-4;
    reduce_kernel<<<1, BLOCK, 0, stream>>>(parts, nparts, out + (out_size - 1), scale);
}

// Round 13
// 190.009 us; speedup vs baseline: 1.0323x; 1.0323x over previous
//
#include <hip/hip_runtime.h>

#define D     512
#define HW    (D * D)
#define BLOCK 256

typedef float f4 __attribute__((ext_vector_type(4)));   // native vec for NT stores

// ---------------------------------------------------------------------------
// R13 = R9 (best measured: role-split, edge blocks first, branch-free fast
// blocks, deferred NT stores) + fused loss reduction: no reduce_kernel, no
// partials array. Per-block LDS reduce -> ONE pre-scaled f32 atomicAdd into
// out[out_size-1] (zeroed via 4-byte hipMemsetAsync before launch).
// 2 fewer dispatches on the stream; partials round-trip eliminated.
// ---------------------------------------------------------------------------

// Block-uniform corner sample values (exact f32 replication of reference):
//   S = WF*WF*p(510,510) + WC*WF*p(511,510) + WF*WC*p(510,511) + WC*WC*p(511,511)
__device__ __forceinline__ void corner_vals(const float* __restrict__ base1,
    const float* __restrict__ base2, float S1[3], float S2[3])
{
    const float WF = 1.0f - (510.999f - 510.0f);   // x/y-floor weight
    const float WC = 1.0f - (511.0f - 510.999f);   // x/y-ceil  weight
#pragma unroll
    for (int c = 0; c < 3; ++c) {
        const float* c1 = base1 + (size_t)c * HW;
        const float* c2 = base2 + (size_t)c * HW;
        S1[c] = (WF * WF) * c1[510 + D * 510] + (WC * WF) * c1[510 + D * 511]
              + (WF * WC) * c1[511 + D * 510] + (WC * WC) * c1[511 + D * 511];
        S2[c] = (WF * WF) * c2[510 + D * 510] + (WC * WF) * c2[510 + D * 511]
              + (WF * WC) * c2[511 + D * 510] + (WC * WC) * c2[511 + D * 511];
    }
}

// Fast-path per-pixel math (identical expressions to previous passing kernel).
__device__ __forceinline__ void fast_px(float fi, float fj, float cx, float cy,
    float m1, float m2, const float S1[3], const float S2[3],
    float* oob, float r[3])
{
    float tot = m1 + m2;
    float inv = 1.0f / tot;
    float m1n = m1 * inv, m2n = m2 * inv;
    float rx1 = (fi + cx) * 512.0f, ry1 = (fj + cy) * 512.0f;
    float rx2 = (fi - cx) * 512.0f, ry2 = (fj - cy) * 512.0f;
    float dx1 = rx1 - 510.999f, dy1 = ry1 - 510.999f;
    float dx2 = rx2 - 510.999f, dy2 = ry2 - 510.999f;
    *oob += dx1 * dx1 + dy1 * dy1 + dx2 * dx2 + dy2 * dy2;
    r[0] = m1n * S1[0] + m2n * S2[0];
    r[1] = m1n * S1[1] + m2n * S2[1];
    r[2] = m1n * S1[2] + m2n * S2[2];
}

// General path: full reference bilinear with per-lane gathers (ind = y + D*x).
__device__ __forceinline__ void samp_gather(const float* __restrict__ im,
    float rx, float ry, float m, float r3[3], float* oob)
{
    float cxq = fminf(fmaxf(rx, 0.001f), 510.999f);
    float cyq = fminf(fmaxf(ry, 0.001f), 510.999f);
    float dx = rx - cxq, dy = ry - cyq;
    *oob += dx * dx + dy * dy;
    float xff = floorf(cxq), xcf = ceilf(cxq);
    float yff = floorf(cyq), ycf = ceilf(cyq);
    float wxf = 1.0f - (cxq - xff), wxc = 1.0f - (xcf - cxq);
    float wyf = 1.0f - (cyq - yff), wyc = 1.0f - (ycf - cyq);
    float w00 = wxf * wyf, w10 = wxc * wyf, w01 = wxf * wyc, w11 = wxc * wyc;
    int xf = (int)xff, xc = (int)xcf, yf = (int)yff, yc = (int)ycf;
    int i00 = yf + D * xf, i10 = yf + D * xc;
    int i01 = yc + D * xf, i11 = yc + D * xc;
#pragma unroll
    for (int c = 0; c < 3; ++c) {
        const float* __restrict__ ch = im + (size_t)c * HW;
        r3[c] += m * (w00 * ch[i00] + w10 * ch[i10] + w01 * ch[i01] + w11 * ch[i11]);
    }
}

// Full reference per-pixel (round-0 proven body): writes out, adds full oob.
__device__ __forceinline__ void ref_px(const float* __restrict__ base1,
    const float* __restrict__ base2, const float S1[3], const float S2[3],
    int i, int j, float cx, float cy, float m1v, float m2v,
    float* __restrict__ outp, size_t ob_pp, float* oob)
{
    float tot = m1v + m2v;
    float inv = 1.0f / tot;
    float m1n = m1v * inv, m2n = m2v * inv;
    float fi = (float)i, fj = (float)j;

    float rx1 = (fi + cx) * 512.0f, ry1 = (fj + cy) * 512.0f;
    float rx2 = (fi - cx) * 512.0f, ry2 = (fj - cy) * 512.0f;

    // exact: (fi - |cx|)*512 == min(rx1, rx2) (f32 sub + pow2 mul are exact)
    bool fast = ((fi - fabsf(cx)) * 512.0f >= 510.999f)
             && ((fj - fabsf(cy)) * 512.0f >= 510.999f);

    float r3[3];
    if (fast) {
        float dx1 = rx1 - 510.999f, dy1 = ry1 - 510.999f;
        float dx2 = rx2 - 510.999f, dy2 = ry2 - 510.999f;
        *oob += dx1 * dx1 + dy1 * dy1 + dx2 * dx2 + dy2 * dy2;
        r3[0] = m1n * S1[0] + m2n * S2[0];
        r3[1] = m1n * S1[1] + m2n * S2[1];
        r3[2] = m1n * S1[2] + m2n * S2[2];
    } else {
        r3[0] = r3[1] = r3[2] = 0.0f;
        samp_gather(base1, rx1, ry1, m1n, r3, oob);
        samp_gather(base2, rx2, ry2, m2n, r3, oob);
    }
    outp[ob_pp]          = r3[0];
    outp[ob_pp + HW]     = r3[1];
    outp[ob_pp + 2 * HW] = r3[2];
}

__device__ __forceinline__ void nt_store4(float* p, const float r[4])
{
    f4 v = {r[0], r[1], r[2], r[3]};
    __builtin_nontemporal_store(v, (f4*)p);
}

// Grid = N*32 edge blocks (first) + N*126 fast blocks (8 px per thread).
__global__ void __launch_bounds__(BLOCK) main_kernel(
    const float* __restrict__ im1, const float* __restrict__ im2,
    const float* __restrict__ C,   const float* __restrict__ M1,
    const float* __restrict__ M2,  float* __restrict__ out,
    float* __restrict__ loss_out, float scale, int eblocks)
{
    int b = blockIdx.x;
    int t = threadIdx.x;
    float oob = 0.0f;

    if (b < eblocks) {
        // ---------------- edge blocks: strip rows 0..7  U  cols 0..7 -------
        int n  = b >> 5;
        int rb = b & 31;

        const float* base1 = im1 + (size_t)n * 3 * HW;
        const float* base2 = im2 + (size_t)n * 3 * HW;
        float S1[3], S2[3];
        corner_vals(base1, base2, S1, S2);

        int i, j; bool valid;
        if (rb < 16) {                   // region A: rows 0..7, half-row each
            i = rb >> 1;
            j = ((rb & 1) << 8) + t;
            valid = true;
        } else {                         // region B: rows 8..511, cols 0..7
            int q = rb - 16;             // 0..15
            i = 8 + (q << 5) + (t >> 3);
            j = t & 7;
            valid = (i < D);
        }

        if (valid) {
            size_t cb = (size_t)n * 2 * HW, mb = (size_t)n * HW;
            size_t ob = (size_t)n * 3 * HW;
            size_t pp = (size_t)i * D + j;
            ref_px(base1, base2, S1, S2, i, j,
                   C[cb + pp], C[cb + HW + pp], M1[mb + pp], M2[mb + pp],
                   out, ob + pp, &oob);
        }
    } else {
        // ---------------- fast blocks: rows 8..511, col-groups 2..127 ------
        int nb = b - eblocks;
        int n  = nb / 126;               // 126 blocks per image
        int ib = nb - n * 126;

        const float* base1 = im1 + (size_t)n * 3 * HW;
        const float* base2 = im2 + (size_t)n * 3 * HW;
        float S1[3], S2[3];
        corner_vals(base1, base2, S1, S2);

        size_t cb = (size_t)n * 2 * HW, mb = (size_t)n * HW;
        size_t ob = (size_t)n * 3 * HW;

        int g0 = (ib << 9) + t;          // group index over rows 8..511
        int g1 = g0 + 256;
        int row0 = 8 + (g0 >> 7), col0 = (g0 & 127) << 2;
        int row1 = 8 + (g1 >> 7), col1 = (g1 & 127) << 2;
        size_t p0 = ((size_t)row0 << 9) + col0;
        size_t p1 = ((size_t)row1 << 9) + col1;
        bool own = (t & 127) >= 2;       // col-groups 0,1 belong to edge blocks

        float4 cxa = *(const float4*)(C  + cb + p0);
        float4 cya = *(const float4*)(C  + cb + HW + p0);
        float4 m1a = *(const float4*)(M1 + mb + p0);
        float4 m2a = *(const float4*)(M2 + mb + p0);
        float4 cxb = *(const float4*)(C  + cb + p1);
        float4 cyb = *(const float4*)(C  + cb + HW + p1);
        float4 m1b = *(const float4*)(M1 + mb + p1);
        float4 m2b = *(const float4*)(M2 + mb + p1);

        // ---- compute ALL 8 px into registers; NO stores inside the chain ----
        float o0a[4], o1a[4], o2a[4];    // chunk 0 outputs (ch0/ch1/ch2)
        float o0b[4], o1b[4], o2b[4];    // chunk 1 outputs
        {
            float fi = (float)row0, fj = (float)col0;
            float ra[3], rbv[3], rc[3], rd[3];
            fast_px(fi, fj + 0.0f, cxa.x, cya.x, m1a.x, m2a.x, S1, S2, &oob, ra);
            fast_px(fi, fj + 1.0f, cxa.y, cya.y, m1a.y, m2a.y, S1, S2, &oob, rbv);
            fast_px(fi, fj + 2.0f, cxa.z, cya.z, m1a.z, m2a.z, S1, S2, &oob, rc);
            fast_px(fi, fj + 3.0f, cxa.w, cya.w, m1a.w, m2a.w, S1, S2, &oob, rd);
            o0a[0]=ra[0]; o0a[1]=rbv[0]; o0a[2]=rc[0]; o0a[3]=rd[0];
            o1a[0]=ra[1]; o1a[1]=rbv[1]; o1a[2]=rc[1]; o1a[3]=rd[1];
            o2a[0]=ra[2]; o2a[1]=rbv[2]; o2a[2]=rc[2]; o2a[3]=rd[2];
        }
        {
            float fi = (float)row1, fj = (float)col1;
            float ra[3], rbv[3], rc[3], rd[3];
            fast_px(fi, fj + 0.0f, cxb.x, cyb.x, m1b.x, m2b.x, S1, S2, &oob, ra);
            fast_px(fi, fj + 1.0f, cxb.y, cyb.y, m1b.y, m2b.y, S1, S2, &oob, rbv);
            fast_px(fi, fj + 2.0f, cxb.z, cyb.z, m1b.z, m2b.z, S1, S2, &oob, rc);
            fast_px(fi, fj + 3.0f, cxb.w, cyb.w, m1b.w, m2b.w, S1, S2, &oob, rd);
            o0b[0]=ra[0]; o0b[1]=rbv[0]; o0b[2]=rc[0]; o0b[3]=rd[0];
            o1b[0]=ra[1]; o1b[1]=rbv[1]; o1b[2]=rc[1]; o1b[3]=rd[1];
            o2b[0]=ra[2]; o2b[1]=rbv[2]; o2b[2]=rc[2]; o2b[3]=rd[2];
        }

        // ---- all stores at the end (nontemporal; nothing waits on them) ----
        if (own) {
            nt_store4(out + ob + p0,          o0a);
            nt_store4(out + ob + HW + p0,     o1a);
            nt_store4(out + ob + 2 * HW + p0, o2a);
            nt_store4(out + ob + p1,          o0b);
            nt_store4(out + ob + HW + p1,     o1b);
            nt_store4(out + ob + 2 * HW + p1, o2b);
        }
        if (!own) oob = 0.0f;            // those pixels are owned by edge blocks
    }

    // ---- fused loss reduction: wave shuffle -> LDS -> one atomic/block ----
    for (int off = 32; off > 0; off >>= 1)
        oob += __shfl_down(oob, off, 64);

    __shared__ float sred[BLOCK / 64];
    int lane = t & 63, w = t >> 6;
    if (lane == 0) sred[w] = oob;
    __syncthreads();
    if (t == 0) {
        float blk = (sred[0] + sred[1] + sred[2] + sred[3]) * scale;
        atomicAdd(loss_out, blk);        // device-scope; ~2528 spread atomics
    }
}

extern "C" void kernel_launch(void* const* d_in, const int* in_sizes, int n_in,
                              void* d_out, int out_size, void* d_ws, size_t ws_size,
                              hipStream_t stream) {
    const float* im1 = (const float*)d_in[0];
    const float* im2 = (const float*)d_in[1];
    const float* C   = (const float*)d_in[2];
    const float* M1  = (const float*)d_in[3];
    const float* M2  = (const float*)d_in[4];
    float* out = (float*)d_out;

    int N = in_sizes[3] / HW;        // M1 is [N,1,H,W]
    int eblocks = N * 32;            // edge blocks first (overlap with bulk)
    int fblocks = N * 126;           // rows 8..511, 512 groups per block
    int blocks  = eblocks + fblocks;

    float* loss_out = out + (out_size - 1);
    // loss = sum / (N*2*HW) / D^2 * 1e-4  (a and b share the mean count)
    double scaled = 1.0 / ((double)N * 2.0 * (double)HW) / (double)HW * 1e-4;
    float scale = (float)scaled;

    hipMemsetAsync(loss_out, 0, sizeof(float), stream);   // stream-ordered zero
    main_kernel<<<blocks, BLOCK, 0, stream>>>(im1, im2, C, M1, M2, out,
                                              loss_out, scale, eblocks);
}